// Round 1
// baseline (404.809 us; speedup 1.0000x reference)
//
#include <hip/hip_runtime.h>
#include <stdint.h>

// sign-binarized 3x3 conv via XNOR-popcount.
// N=32, Cin=Cout=256, H=W=56, K=3, pad=1, stride=1.
//
// ws layout:
//   xb   : packed activations with zero halo, [N][58][58][4] u64  (channel-packed)
//   wb   : packed weights [Cout][9 taps][4] u64
//   wcorr: per-(co, edge-pattern) popcount correction, [Cout][9] u32

#define CIN  256
#define COUT 256
#define HH   56
#define WW   56
#define NN   32
#define HP   58                 // 56 + 2 halo
#define HWI  (HH*WW)            // 3136

typedef unsigned long long u64;
typedef unsigned int u32;

#define XB_BYTES ((size_t)NN*HP*HP*4*8)          // 3,444,736
#define WB_BYTES ((size_t)COUT*9*4*8)            // 73,728
#define WC_BYTES ((size_t)COUT*9*4)              // 9,216

// ---------------- Pass 0: pack weights + edge-pattern corrections ----------
__global__ __launch_bounds__(256) void pack_w_kernel(const float* __restrict__ M,
                                                     u64* __restrict__ wb,
                                                     u32* __restrict__ wcorr) {
    int co   = blockIdx.x;
    int lane = threadIdx.x & 63;
    int cg   = threadIdx.x >> 6;          // channel group 0..3 (one per wave)
    __shared__ u32 pp[9 * 4];
    __shared__ u32 wp[9];

    int c = cg * 64 + lane;
    const float* Mb = M + ((size_t)co * CIN + c) * 9;   // OIHW, 9 taps contiguous
    #pragma unroll
    for (int t = 0; t < 9; ++t) {
        float v = Mb[t];
        u64 b = __ballot(v >= 0.0f);      // bit lane = sign bit of channel c
        if (lane == 0) {
            wb[((size_t)co * 9 + t) * 4 + cg] = b;
            pp[t * 4 + cg] = (u32)__popcll(b);
        }
    }
    __syncthreads();
    if (threadIdx.x < 9) {
        int t = threadIdx.x;
        wp[t] = pp[t*4+0] + pp[t*4+1] + pp[t*4+2] + pp[t*4+3];
    }
    __syncthreads();
    if (threadIdx.x < 9) {
        // edge pattern pid = hs*3+ws; hs/ws: 0=low edge,1=interior,2=high edge
        int pid = threadIdx.x;
        int hs = pid / 3, ws = pid % 3;
        u32 corr = 0;
        #pragma unroll
        for (int t = 0; t < 9; ++t) {
            int dh = t / 3 - 1, dw = t % 3 - 1;
            bool inval = (hs == 0 && dh == -1) || (hs == 2 && dh == 1) ||
                         (ws == 0 && dw == -1) || (ws == 2 && dw == 1);
            if (inval) corr += wp[t];
        }
        wcorr[co * 9 + pid] = corr;
    }
}

// ---------------- Pass 1: binarize x, channel-pack via ballot transpose ----
// One block = one (n,h) row; 4 waves = 4 channel groups; lanes = w positions.
__global__ __launch_bounds__(256) void pack_x_kernel(const float* __restrict__ x,
                                                     u64* __restrict__ xb) {
    int nh   = blockIdx.x;                // n*56 + h
    int n    = nh / HH;
    int h    = nh - n * HH;
    int lane = threadIdx.x & 63;
    int cg   = threadIdx.x >> 6;
    int wl   = lane < WW ? lane : WW - 1; // clamp to stay in-bounds

    const float* xr = x + (((size_t)n * CIN + cg * 64) * HH + h) * WW + wl;
    u64 acc = 0;
    #pragma unroll
    for (int c = 0; c < 64; ++c) {
        float v = xr[(size_t)c * HWI];    // channel stride = H*W
        u64 b = __ballot(v >= 0.0f);      // bit j = sign of pixel w=j, channel c
        acc |= ((b >> lane) & 1ull) << c; // lane j gathers its pixel's channel bit
    }
    if (lane < WW)
        xb[(((size_t)n * HP + (h + 1)) * HP + (lane + 1)) * 4 + cg] = acc;
}

// ---------------- Pass 2: XNOR-popcount conv --------------------------------
// One thread = one output pixel, loops over all 256 co.
// 36 u64 activation words live in registers across the co loop; weight words
// are wave-uniform -> scalar loads.
__global__ __launch_bounds__(256) void conv_kernel(const u64* __restrict__ xb,
                                                   const u64* __restrict__ wb,
                                                   const u32* __restrict__ wcorr,
                                                   const float* __restrict__ alpha,
                                                   float* __restrict__ out) {
    int p   = blockIdx.x * 256 + threadIdx.x;   // 0 .. 100351
    int n   = p / HWI;
    int rem = p - n * HWI;
    int h   = rem / WW;
    int w   = rem - h * WW;

    // load 9 taps x 4 u64 (32B contiguous per tap, compile-time offsets)
    const u64* base = xb + (((size_t)n * HP + h) * HP + w) * 4;
    u64 a[36];
    #pragma unroll
    for (int t = 0; t < 9; ++t) {
        #pragma unroll
        for (int j = 0; j < 4; ++j)
            a[t * 4 + j] = base[((t / 3) * HP + (t % 3)) * 4 + j];
    }

    int hs = (h == 0) ? 0 : ((h == HH - 1) ? 2 : 1);
    int ws = (w == 0) ? 0 : ((w == WW - 1) ? 2 : 1);
    int pid = hs * 3 + ws;
    int nv  = ((hs == 1) ? 3 : 2) * ((ws == 1) ? 3 : 2);  // # valid taps
    int basesum = 256 * nv;

    const u32* wcp = wcorr + pid;
    float* op = out + (size_t)n * COUT * HWI + rem;

    #pragma unroll 2
    for (int co = 0; co < COUT; ++co) {
        const u64* wq = wb + co * 36;     // uniform -> s_load
        u32 P = 0;
        #pragma unroll
        for (int k = 0; k < 36; ++k)
            P += (u32)__popcll(a[k] ^ wq[k]);
        P -= wcp[co * 9];                 // remove halo taps' popc(w) pollution
        float s = (float)(basesum - 2 * (int)P);
        op[(size_t)co * HWI] = s * alpha[co];
    }
}

extern "C" void kernel_launch(void* const* d_in, const int* in_sizes, int n_in,
                              void* d_out, int out_size, void* d_ws, size_t ws_size,
                              hipStream_t stream) {
    const float* x     = (const float*)d_in[0];
    const float* M     = (const float*)d_in[1];
    const float* alpha = (const float*)d_in[2];
    float* out = (float*)d_out;

    char* ws = (char*)d_ws;
    u64* xb    = (u64*)ws;
    u64* wb    = (u64*)(ws + XB_BYTES);
    u32* wcorr = (u32*)(ws + XB_BYTES + WB_BYTES);

    // zero halo (and interior; interior gets overwritten by pack_x)
    hipMemsetAsync(xb, 0, XB_BYTES, stream);
    pack_w_kernel<<<COUT, 256, 0, stream>>>(M, wb, wcorr);
    pack_x_kernel<<<NN * HH, 256, 0, stream>>>(x, xb);
    conv_kernel<<<(NN * HWI) / 256, 256, 0, stream>>>(xb, wb, wcorr, alpha, out);
}

// Round 4
// 300.160 us; speedup vs baseline: 1.3486x; 1.3486x over previous
//
#include <hip/hip_runtime.h>
#include <stdint.h>

// sign-binarized 3x3 conv via XNOR-popcount.
// N=32, Cin=Cout=256, H=W=56, K=3, pad=1, stride=1.
//
// ws layout:
//   xb   : packed activations with zero halo, [N][58][58][4] u64  (channel-packed)
//   wb   : packed weights [Cout][9 taps][4] u64
//   wcorr: per-(co, edge-pattern) popcount correction, [Cout][9] u32

#define CIN  256
#define COUT 256
#define HH   56
#define WW   56
#define NN   32
#define HP   58                 // 56 + 2 halo
#define HWI  (HH*WW)            // 3136
#define CO_CHUNK 32             // co per block in conv (grid.y = COUT/CO_CHUNK)

typedef unsigned long long u64;
typedef unsigned int u32;

#define XB_BYTES ((size_t)NN*HP*HP*4*8)          // 3,444,736
#define WB_BYTES ((size_t)COUT*9*4*8)            // 73,728
#define WC_BYTES ((size_t)COUT*9*4)              // 9,216

// ---------------- Pass 0: pack weights + edge-pattern corrections ----------
__global__ __launch_bounds__(256) void pack_w_kernel(const float* __restrict__ M,
                                                     u64* __restrict__ wb,
                                                     u32* __restrict__ wcorr) {
    int co   = blockIdx.x;
    int lane = threadIdx.x & 63;
    int cg   = threadIdx.x >> 6;          // channel group 0..3 (one per wave)
    __shared__ u32 pp[9 * 4];
    __shared__ u32 wp[9];

    int c = cg * 64 + lane;
    const float* Mb = M + ((size_t)co * CIN + c) * 9;   // OIHW, 9 taps contiguous
    #pragma unroll
    for (int t = 0; t < 9; ++t) {
        float v = Mb[t];
        u64 b = __ballot(v >= 0.0f);      // bit lane = sign bit of channel c
        if (lane == 0) {
            wb[((size_t)co * 9 + t) * 4 + cg] = b;
            pp[t * 4 + cg] = (u32)__popcll(b);
        }
    }
    __syncthreads();
    if (threadIdx.x < 9) {
        int t = threadIdx.x;
        wp[t] = pp[t*4+0] + pp[t*4+1] + pp[t*4+2] + pp[t*4+3];
    }
    __syncthreads();
    if (threadIdx.x < 9) {
        // edge pattern pid = hs*3+ws; hs/ws: 0=low edge,1=interior,2=high edge
        int pid = threadIdx.x;
        int hs = pid / 3, ws = pid % 3;
        u32 corr = 0;
        #pragma unroll
        for (int t = 0; t < 9; ++t) {
            int dh = t / 3 - 1, dw = t % 3 - 1;
            bool inval = (hs == 0 && dh == -1) || (hs == 2 && dh == 1) ||
                         (ws == 0 && dw == -1) || (ws == 2 && dw == 1);
            if (inval) corr += wp[t];
        }
        wcorr[co * 9 + pid] = corr;
    }
}

// ---------------- Pass 1: binarize x, channel-pack via ballot transpose ----
// One block = one (n,h) row; 4 waves = 4 channel groups; lanes = w positions.
// unroll bounded to 8 to keep in-flight loads (and VGPRs) sane.
__global__ __launch_bounds__(256) void pack_x_kernel(const float* __restrict__ x,
                                                     u64* __restrict__ xb) {
    int nh   = blockIdx.x;                // n*56 + h
    int n    = nh / HH;
    int h    = nh - n * HH;
    int lane = threadIdx.x & 63;
    int cg   = threadIdx.x >> 6;
    int wl   = lane < WW ? lane : WW - 1; // clamp to stay in-bounds

    const float* xr = x + (((size_t)n * CIN + cg * 64) * HH + h) * WW + wl;
    u32 lo = 0, hi = 0;
    #pragma unroll 8
    for (int c = 0; c < 32; ++c) {
        u64 b = __ballot(xr[(size_t)c * HWI] >= 0.0f);
        lo |= (u32)((b >> lane) & 1ull) << c;
    }
    #pragma unroll 8
    for (int c = 0; c < 32; ++c) {
        u64 b = __ballot(xr[(size_t)(c + 32) * HWI] >= 0.0f);
        hi |= (u32)((b >> lane) & 1ull) << c;
    }
    if (lane < WW) {
        u64 acc = ((u64)hi << 32) | lo;
        xb[(((size_t)n * HP + (h + 1)) * HP + (lane + 1)) * 4 + cg] = acc;
    }
}

// ---------------- Pass 2: XNOR-popcount conv --------------------------------
// One thread = one output pixel; block handles CO_CHUNK consecutive co.
// grid = (N*H*W/256, COUT/CO_CHUNK) = (392, 8) -> 12544 waves, ~4 waves/SIMD
// (VGPR-limited) so weight s_load latency is hidden.
// a[36] is PINNED in VGPRs via empty asm: round-1 compile sank these loads
// into the co loop (VGPR_Count=48 < 72 needed), re-reading xb 32x per pixel.
__global__ __launch_bounds__(256, 2) void conv_kernel(const u64* __restrict__ xb,
                                                      const u64* __restrict__ wb,
                                                      const u32* __restrict__ wcorr,
                                                      const float* __restrict__ alpha,
                                                      float* __restrict__ out) {
    int p   = blockIdx.x * 256 + threadIdx.x;   // 0 .. 100351
    int c0  = blockIdx.y * CO_CHUNK;
    int n   = p / HWI;
    int rem = p - n * HWI;
    int h   = rem / WW;
    int w   = rem - h * WW;

    // load 9 taps x 4 u64 (32B contiguous per tap -> 2x dwordx4 each)
    const u64* base = xb + (((size_t)n * HP + h) * HP + w) * 4;
    u64 a[36];
    #pragma unroll
    for (int t = 0; t < 9; ++t) {
        #pragma unroll
        for (int j = 0; j < 4; ++j)
            a[t * 4 + j] = base[((t / 3) * HP + (t % 3)) * 4 + j];
    }
    // Pin activation words in VGPRs; forbids load-sinking/remat into co loop.
    #pragma unroll
    for (int k = 0; k < 36; ++k) asm volatile("" : "+v"(a[k]));

    int hs = (h == 0) ? 0 : ((h == HH - 1) ? 2 : 1);
    int ws = (w == 0) ? 0 : ((w == WW - 1) ? 2 : 1);
    int pid = hs * 3 + ws;
    int nv  = ((hs == 1) ? 3 : 2) * ((ws == 1) ? 3 : 2);  // # valid taps
    int basesum = 256 * nv;

    const u32* wcp = wcorr + pid + (size_t)c0 * 9;
    const float* alp = alpha + c0;
    float* op = out + (size_t)n * COUT * HWI + (size_t)c0 * HWI + rem;

    #pragma unroll 2
    for (int co = 0; co < CO_CHUNK; ++co) {
        const u64* wq = wb + (size_t)(c0 + co) * 36;  // uniform -> s_load
        u32 P0 = 0, P1 = 0;                           // 2 chains: halve dep latency
        #pragma unroll
        for (int k = 0; k < 18; ++k) {
            P0 += (u32)__popcll(a[2*k]     ^ wq[2*k]);
            P1 += (u32)__popcll(a[2*k + 1] ^ wq[2*k + 1]);
        }
        u32 P = P0 + P1 - wcp[co * 9];    // remove halo taps' popc(w) pollution
        float s = (float)(basesum - 2 * (int)P);
        __builtin_nontemporal_store(s * alp[co], &op[(size_t)co * HWI]);
    }
}

extern "C" void kernel_launch(void* const* d_in, const int* in_sizes, int n_in,
                              void* d_out, int out_size, void* d_ws, size_t ws_size,
                              hipStream_t stream) {
    const float* x     = (const float*)d_in[0];
    const float* M     = (const float*)d_in[1];
    const float* alpha = (const float*)d_in[2];
    float* out = (float*)d_out;

    char* ws = (char*)d_ws;
    u64* xb    = (u64*)ws;
    u64* wb    = (u64*)(ws + XB_BYTES);
    u32* wcorr = (u32*)(ws + XB_BYTES + WB_BYTES);

    // zero halo (and interior; interior gets overwritten by pack_x)
    hipMemsetAsync(xb, 0, XB_BYTES, stream);
    pack_w_kernel<<<COUT, 256, 0, stream>>>(M, wb, wcorr);
    pack_x_kernel<<<NN * HH, 256, 0, stream>>>(x, xb);
    dim3 cgrid((NN * HWI) / 256, COUT / CO_CHUNK);
    conv_kernel<<<cgrid, 256, 0, stream>>>(xb, wb, wcorr, alpha, out);
}

// Round 6
// 293.112 us; speedup vs baseline: 1.3811x; 1.0240x over previous
//
#include <hip/hip_runtime.h>
#include <stdint.h>

// sign-binarized 3x3 conv via XNOR-popcount.
// N=32, Cin=Cout=256, H=W=56, K=3, pad=1, stride=1.
//
// ws layout:
//   xb   : packed activations with zero halo, [N][58][58][4] u64  (channel-packed)
//   wb   : packed weights [Cout][9 taps][4] u64  (= [Cout][72] u32)
//   wcorr: per-(edge-pattern, co) popcount correction, [9][COUT] u32

#define CIN  256
#define COUT 256
#define HH   56
#define WW   56
#define NN   32
#define HP   58                 // 56 + 2 halo
#define HWI  (HH*WW)            // 3136
#define CO_CHUNK 32             // co per block in conv (grid.y = COUT/CO_CHUNK)

typedef unsigned long long u64;
typedef unsigned int u32;

#define XB_BYTES ((size_t)NN*HP*HP*4*8)          // 3,444,736
#define WB_BYTES ((size_t)COUT*9*4*8)            // 73,728
#define WC_BYTES ((size_t)9*COUT*4)              // 9,216

// ---------------- Pass 0: pack weights + edge-pattern corrections ----------
__global__ __launch_bounds__(256) void pack_w_kernel(const float* __restrict__ M,
                                                     u64* __restrict__ wb,
                                                     u32* __restrict__ wcorr) {
    int co   = blockIdx.x;
    int lane = threadIdx.x & 63;
    int cg   = threadIdx.x >> 6;          // channel group 0..3 (one per wave)
    __shared__ u32 pp[9 * 4];
    __shared__ u32 wp[9];

    int c = cg * 64 + lane;
    const float* Mb = M + ((size_t)co * CIN + c) * 9;   // OIHW, 9 taps contiguous
    #pragma unroll
    for (int t = 0; t < 9; ++t) {
        float v = Mb[t];
        u64 b = __ballot(v >= 0.0f);      // bit lane = sign bit of channel c
        if (lane == 0) {
            wb[((size_t)co * 9 + t) * 4 + cg] = b;
            pp[t * 4 + cg] = (u32)__popcll(b);
        }
    }
    __syncthreads();
    if (threadIdx.x < 9) {
        int t = threadIdx.x;
        wp[t] = pp[t*4+0] + pp[t*4+1] + pp[t*4+2] + pp[t*4+3];
    }
    __syncthreads();
    if (threadIdx.x < 9) {
        // edge pattern pid = hs*3+ws; hs/ws: 0=low edge,1=interior,2=high edge
        int pid = threadIdx.x;
        int hs = pid / 3, ws = pid % 3;
        u32 corr = 0;
        #pragma unroll
        for (int t = 0; t < 9; ++t) {
            int dh = t / 3 - 1, dw = t % 3 - 1;
            bool inval = (hs == 0 && dh == -1) || (hs == 2 && dh == 1) ||
                         (ws == 0 && dw == -1) || (ws == 2 && dw == 1);
            if (inval) corr += wp[t];
        }
        wcorr[pid * COUT + co] = corr;    // [pid][co] so conv reads with imm offset
    }
}

// ---------------- Pass 1: binarize x, channel-pack via ballot transpose ----
// One block = one (n,h) row; 4 waves = 4 channel groups; lanes = w positions.
// unroll 16 for memory-level parallelism (16 coalesced 256B loads in flight).
__global__ __launch_bounds__(256) void pack_x_kernel(const float* __restrict__ x,
                                                     u64* __restrict__ xb) {
    int nh   = blockIdx.x;                // n*56 + h
    int n    = nh / HH;
    int h    = nh - n * HH;
    int lane = threadIdx.x & 63;
    int cg   = threadIdx.x >> 6;
    int wl   = lane < WW ? lane : WW - 1; // clamp to stay in-bounds

    const float* xr = x + (((size_t)n * CIN + cg * 64) * HH + h) * WW + wl;
    u32 lo = 0, hi = 0;
    #pragma unroll 16
    for (int c = 0; c < 32; ++c) {
        u64 b = __ballot(xr[(size_t)c * HWI] >= 0.0f);
        lo |= (u32)((b >> lane) & 1ull) << c;
    }
    #pragma unroll 16
    for (int c = 0; c < 32; ++c) {
        u64 b = __ballot(xr[(size_t)(c + 32) * HWI] >= 0.0f);
        hi |= (u32)((b >> lane) & 1ull) << c;
    }
    if (lane < WW) {
        u64 acc = ((u64)hi << 32) | lo;
        xb[(((size_t)n * HP + (h + 1)) * HP + (lane + 1)) * 4 + cg] = acc;
    }
}

// ---------------- Pass 2: XNOR-popcount conv --------------------------------
// One thread = one output pixel; block handles CO_CHUNK consecutive co.
// Weights staged in LDS (9 KB/block), read via broadcast ds_read_b128 --
// removes the SGPR-budget s_load stalls seen in round 4 (VALUBusy 83%,
// 2.4x issue floor). a[72] u32 pinned in VGPRs across the co loop.
__global__ __launch_bounds__(256, 4) void conv_kernel(const u64* __restrict__ xb,
                                                      const u64* __restrict__ wb,
                                                      const u32* __restrict__ wcorr,
                                                      const float* __restrict__ alpha,
                                                      float* __restrict__ out) {
    __shared__ u32 w_lds[CO_CHUNK * 72];        // 9216 B

    int tid = threadIdx.x;
    int p   = blockIdx.x * 256 + tid;           // 0 .. 100351
    int c0  = blockIdx.y * CO_CHUNK;
    int n   = p / HWI;
    int rem = p - n * HWI;
    int h   = rem / WW;
    int w   = rem - h * WW;

    // ---- stage weights: 2304 u32 = 576 uint4; 256 threads: 256+256+64 ----
    const uint4* wsrc = (const uint4*)(wb + (size_t)c0 * 36);
    uint4* wdst = (uint4*)w_lds;
    uint4 s0 = wsrc[tid];
    uint4 s1 = wsrc[tid + 256];
    uint4 s2 = wsrc[512 + (tid & 63)];          // always in-bounds; stored if tid<64

    // ---- load 9 taps x 8 u32 of activations (32B/tap, 2x dwordx4) ----
    const u32* base = (const u32*)(xb + (((size_t)n * HP + h) * HP + w) * 4);
    u32 a[72];
    #pragma unroll
    for (int t = 0; t < 9; ++t) {
        const uint4* tb = (const uint4*)(base + ((t / 3) * HP + (t % 3)) * 8);
        uint4 v0 = tb[0], v1 = tb[1];
        a[t*8+0]=v0.x; a[t*8+1]=v0.y; a[t*8+2]=v0.z; a[t*8+3]=v0.w;
        a[t*8+4]=v1.x; a[t*8+5]=v1.y; a[t*8+6]=v1.z; a[t*8+7]=v1.w;
    }

    wdst[tid]       = s0;
    wdst[tid + 256] = s1;
    if (tid < 64) wdst[512 + tid] = s2;
    __syncthreads();

    // Pin activation words in VGPRs; forbids load-sinking/remat into co loop.
    #pragma unroll
    for (int k = 0; k < 72; ++k) asm volatile("" : "+v"(a[k]));

    int hs = (h == 0) ? 0 : ((h == HH - 1) ? 2 : 1);
    int ws = (w == 0) ? 0 : ((w == WW - 1) ? 2 : 1);
    int pid = hs * 3 + ws;
    int nv  = ((hs == 1) ? 3 : 2) * ((ws == 1) ? 3 : 2);  // # valid taps
    float basesum = (float)(256 * nv);

    const u32* wcp = wcorr + pid * COUT + c0;   // per-co: dword load, imm offset
    const float* alp = alpha + c0;
    float* op = out + (size_t)n * COUT * HWI + (size_t)c0 * HWI + rem;

    for (int co = 0; co < CO_CHUNK; ++co) {
        const u32* wq = &w_lds[co * 72];        // broadcast ds_read_b128 x18
        u32 P0 = 0, P1 = 0, P2 = 0, P3 = 0;    // 4 chains: v_bcnt accum fusion
        #pragma unroll
        for (int k = 0; k < 72; k += 4) {
            P0 += __builtin_popcount(a[k]     ^ wq[k]);
            P1 += __builtin_popcount(a[k + 1] ^ wq[k + 1]);
            P2 += __builtin_popcount(a[k + 2] ^ wq[k + 2]);
            P3 += __builtin_popcount(a[k + 3] ^ wq[k + 3]);
        }
        u32 P = (P0 + P1) + (P2 + P3) - wcp[co];  // remove halo taps' popc(w)
        float s = basesum - 2.0f * (float)(int)P;
        __builtin_nontemporal_store(s * alp[co], &op[(size_t)co * HWI]);
    }
}

extern "C" void kernel_launch(void* const* d_in, const int* in_sizes, int n_in,
                              void* d_out, int out_size, void* d_ws, size_t ws_size,
                              hipStream_t stream) {
    const float* x     = (const float*)d_in[0];
    const float* M     = (const float*)d_in[1];
    const float* alpha = (const float*)d_in[2];
    float* out = (float*)d_out;

    char* ws = (char*)d_ws;
    u64* xb    = (u64*)ws;
    u64* wb    = (u64*)(ws + XB_BYTES);
    u32* wcorr = (u32*)(ws + XB_BYTES + WB_BYTES);

    // zero halo (and interior; interior gets overwritten by pack_x)
    hipMemsetAsync(xb, 0, XB_BYTES, stream);
    pack_w_kernel<<<COUT, 256, 0, stream>>>(M, wb, wcorr);
    pack_x_kernel<<<NN * HH, 256, 0, stream>>>(x, xb);
    dim3 cgrid((NN * HWI) / 256, COUT / CO_CHUNK);
    conv_kernel<<<cgrid, 256, 0, stream>>>(xb, wb, wcorr, alpha, out);
}